// Round 4
// baseline (134.183 us; speedup 1.0000x reference)
//
#include <hip/hip_runtime.h>
#include <math.h>

// ---------------------------------------------------------------------------
// LocalTransformerBlock2d: B=1, C=256, H=W=56 (N=3136), 8 heads x d=32,
// 7x7 local window. fp32 in/out; bf16 MFMA GEMMs.
// R19 (from R18=121.2us): prep/qkv unchanged. attnmlp: weight operands for
// proj/fc1/fc2 now load global->REGISTER (1 dwordx4/lane per MFMA operand)
// instead of global->LDS slab->register. The slab path had zero cross-wave
// reuse and cost ~1.8MB/block of LDS traffic (fc1 786KB + fc2 1MB + proj
// 130KB) through a 128B/cy pipe + vmcnt(2)-gated rings exposing L2 latency
// every iter. Swizzle algebra checked: slab read == w[(16wv+fm)*K + kt*32
// + q*8] exactly, so MFMA inputs are bit-identical.
// Prefetch: proj all-8 preloaded before PV; fc1 depth-2 rotation (prologue
// issued across LN2 barriers); fc2 depth-3 (prologue before hbuf sync).
// ---------------------------------------------------------------------------

typedef unsigned int uint;
typedef unsigned short ushort;
typedef unsigned long long u64;
typedef __attribute__((ext_vector_type(8))) short short8;   // 8 bf16
typedef __attribute__((ext_vector_type(4))) float floatx4;  // MFMA acc
typedef __attribute__((ext_vector_type(4))) unsigned short ushort4v;

#define AS1(p) (const __attribute__((address_space(1))) void*)(p)
#define AS3(p) (__attribute__((address_space(3))) void*)(p)

__device__ __forceinline__ float bf2f(ushort u) {
  union { uint i; float f; } v; v.i = ((uint)u) << 16; return v.f;
}
__device__ __forceinline__ ushort f2bf(float f) {
  union { float f; uint i; } v; v.f = f;
  uint u = v.i;
  return (ushort)((u + 0x7fffu + ((u >> 16) & 1u)) >> 16);
}

// Stage a 64-row x 256-col bf16 panel into LDS with XOR swizzle (qkv kernel).
__device__ __forceinline__ void stage64(const ushort* src, int kstride,
                                        ushort* dstBase, int tid) {
  const int srow = tid >> 5;
  const int scb  = (tid & 31) ^ srow;
  const ushort* g = src + (size_t)srow * kstride + scb * 8;
  ushort* d = dstBase + tid * 8;
  #pragma unroll
  for (int r = 0; r < 8; ++r) {
    __builtin_amdgcn_global_load_lds(AS1(g), AS3(d), 16, 0, 0);
    g += 8 * kstride;
    d += 2048;
  }
}

__device__ __forceinline__ void compute64(const ushort* As, const ushort* Bs,
                                          int w, int lane, floatx4 acc[4]) {
  const int fm = lane & 15;
  const int q  = lane >> 4;
  const int swz = fm & 7;
  const int arow = (w * 16 + fm) * 256;
  #pragma unroll
  for (int kt = 0; kt < 8; ++kt) {
    const int blk = ((kt * 4 + q) ^ swz) * 8;
    short8 af = *(const short8*)&As[arow + blk];
    #pragma unroll
    for (int nt = 0; nt < 4; ++nt) {
      short8 bfr = *(const short8*)&Bs[(nt * 16 + fm) * 256 + blk];
      acc[nt] = __builtin_amdgcn_mfma_f32_16x16x32_bf16(af, bfr, acc[nt], 0, 0, 0);
    }
  }
}

// ---------------------------------------------------------------------------
// prep: blocks 0..195 LN1+transpose (16 px each); blocks 196..387 cvt of
// qkvw (49152 float4s), 1 float4 per thread.
// ---------------------------------------------------------------------------
__global__ __launch_bounds__(256) void prep_kernel(
    const float* __restrict__ x, const float* __restrict__ n1w,
    const float* __restrict__ n1b, const float* __restrict__ qkvw,
    ushort* __restrict__ t1, ushort* __restrict__ wcat)
{
  const int tid = threadIdx.x;
  const int bid = blockIdx.x;
  if (bid >= 196) {
    int idx4 = (bid - 196) * 256 + tid;      // < 49152 float4s
    const float4 v = ((const float4*)qkvw)[idx4];
    ushort4v o = { f2bf(v.x), f2bf(v.y), f2bf(v.z), f2bf(v.w) };
    *(ushort4v*)&wcat[(size_t)idx4 * 4] = o;
    return;
  }
  __shared__ float tile[256 * 17];
  __shared__ float red[2][16][16];
  __shared__ float mu[16], rsv[16];
  const int n0 = bid * 16;
  const int px = tid & 15, grp = tid >> 4;
  {
    // vectorized load: thread c = tid owns channel row c, 16 px = 4 float4
    const float4* xr = (const float4*)&x[(size_t)tid * 3136 + n0];
    #pragma unroll
    for (int k = 0; k < 4; ++k) {
      float4 v = xr[k];
      float* tr = &tile[tid * 17 + k * 4];
      tr[0] = v.x; tr[1] = v.y; tr[2] = v.z; tr[3] = v.w;
    }
  }
  __syncthreads();
  float s = 0.f, ss = 0.f;
  #pragma unroll
  for (int i = 0; i < 16; ++i) {
    float v = tile[(grp * 16 + i) * 17 + px];
    s += v; ss += v * v;
  }
  red[0][px][grp] = s; red[1][px][grp] = ss;
  __syncthreads();
  if (tid < 16) {
    float s2 = 0.f, ss2 = 0.f;
    #pragma unroll
    for (int g = 0; g < 16; ++g) { s2 += red[0][tid][g]; ss2 += red[1][tid][g]; }
    float m = s2 * (1.f / 256.f);
    float var = ss2 * (1.f / 256.f) - m * m;
    mu[tid] = m;
    rsv[tid] = rsqrtf(var + 1e-5f);
  }
  __syncthreads();
  const float wc = n1w[tid], bc = n1b[tid];
  #pragma unroll 4
  for (int p = 0; p < 16; ++p) {
    float v = tile[tid * 17 + p];
    t1[(size_t)(n0 + p) * 256 + tid] = f2bf((v - mu[p]) * rsv[p] * wc + bc);
  }
}

// ---------------------------------------------------------------------------
// qkv: grid (12, 97). y<49: GEMM [3136,256]@[768,256]^T + bias (q scaled).
// y>=49: float4 cvt of pw|f1|f2 (147456 float4s) -- no dependency on GEMM,
// overlaps it and re-warms L2 with weights for attnmlp.
// ---------------------------------------------------------------------------
__global__ __launch_bounds__(256, 4) void qkv_kernel(
    const ushort* __restrict__ A, const ushort* __restrict__ B,
    const float* __restrict__ bias, ushort* __restrict__ out,
    const float* __restrict__ projw, const float* __restrict__ f1w,
    const float* __restrict__ f2w, ushort* __restrict__ wcat)
{
  const int tid = threadIdx.x;
  if (blockIdx.y >= 49) {
    int idx4 = ((blockIdx.y - 49) * 12 + blockIdx.x) * 256 + tid;  // < 147456
    const float* s; int off;
    if (idx4 < 16384)       { s = projw; off = idx4; }
    else if (idx4 < 81920)  { s = f1w;   off = idx4 - 16384; }
    else                    { s = f2w;   off = idx4 - 81920; }
    const float4 v = ((const float4*)s)[off];
    ushort4v o = { f2bf(v.x), f2bf(v.y), f2bf(v.z), f2bf(v.w) };
    *(ushort4v*)&wcat[196608 + (size_t)idx4 * 4] = o;
    return;
  }
  __shared__ ushort As[16384], Bs[16384];
  const int lane = tid & 63, w = tid >> 6;
  const int m0 = blockIdx.y * 64, n0 = blockIdx.x * 64;
  floatx4 acc[4] = {{0.f,0.f,0.f,0.f},{0.f,0.f,0.f,0.f},
                    {0.f,0.f,0.f,0.f},{0.f,0.f,0.f,0.f}};
  stage64(A + (size_t)m0 * 256, 256, As, tid);
  stage64(B + (size_t)n0 * 256, 256, Bs, tid);
  asm volatile("s_waitcnt vmcnt(0)" ::: "memory");
  __syncthreads();
  compute64(As, Bs, w, lane, acc);
  const int fm = lane & 15, q4 = (lane >> 4) * 4;
  #pragma unroll
  for (int nt = 0; nt < 4; ++nt)
    #pragma unroll
    for (int r = 0; r < 4; ++r) {
      int m = m0 + w * 16 + q4 + r;
      int n = n0 + nt * 16 + fm;
      float v = acc[nt][r] + bias[n];
      if (n < 256) v *= 0.17677669529663687f;   // 1/sqrt(32) on q
      out[(size_t)m * 768 + n] = f2bf(v);
    }
}

// ---------------------------------------------------------------------------
// attnmlp: 4x4 query tile per block (grid 196), 1024 threads (4 waves/SIMD).
// LDS (byte offsets; regions reused across phases):
//  attn: Kh@0 (52000) | Vh@52000 (51200) | pr@103200 f32 s67 (34304)
//        aas@137504 (8448) | pstat@145952 (2048) | stats@148000 (128)
//  proj: x1s@103200 f32[16][264] (pr dead)
//  mlp : hbuf@0 (32768) | t2s@120096 [16][256]
// Weights (pw/f1/f2) are register-loaded per lane (no LDS slabs).
// Per-wave ownership: scores q=wv | proj ch [16wv,16wv+16) | fc1 h-cols
// {32wv..+32, 32(wv+16)..+32} | fc2 ch [16wv,16wv+16).
// ---------------------------------------------------------------------------
#define AM_SMEM 148128

__global__ __launch_bounds__(1024, 1) void attnmlp_kernel(
    const ushort* __restrict__ qkv, const ushort* __restrict__ pw_bf,
    const float* __restrict__ projb, const float* __restrict__ x,
    const ushort* __restrict__ f1_bf, const float* __restrict__ f1b,
    const ushort* __restrict__ f2_bf, const float* __restrict__ f2b,
    const float* __restrict__ n2w, const float* __restrict__ n2b,
    float* __restrict__ outf)
{
  __shared__ __align__(16) char smem[AM_SMEM];
  ushort* Kh    = (ushort*)smem;
  ushort* Vh    = (ushort*)(smem + 52000);
  float*  pr    = (float*)(smem + 103200);       // [16*8][67]
  ushort* aas   = (ushort*)(smem + 137504);      // [16][264]
  float*  x1s   = (float*)(smem + 103200);       // [16][264] f32 (pr dead)
  ushort* hbuf  = (ushort*)smem;                 // [16][1024] (Kh dead)
  ushort* t2s   = (ushort*)(smem + 120096);      // [16][256]
  float*  pstat = (float*)(smem + 145952);       // [16][16][2]
  float*  stats = (float*)(smem + 148000);       // [16][2]

  const int tid = threadIdx.x;
  const int wv = tid >> 6, lane = tid & 63;
  const int fm = lane & 15, q = lane >> 4;
  const int i0 = (blockIdx.x / 14) * 4, j0 = (blockIdx.x % 14) * 4;

  // ---- halo load (zero-fill out-of-image) ----
  for (int s = tid; s < 3200; s += 1024) {
    int p = s >> 5, ck = s & 31;
    int ii = i0 - 3 + p / 10, jj = j0 - 3 + p % 10;
    if (ii >= 0 && ii < 56 && jj >= 0 && jj < 56) {
      const ushort* kr = qkv + (size_t)(ii * 56 + jj) * 768 + 256 + ck * 8;
      short8 kv = *(const short8*)kr;
      u64 lo = ((const u64*)&kv)[0], hi = ((const u64*)&kv)[1];
      *(u64*)&Kh[p * 260 + ck * 8] = lo;
      *(u64*)&Kh[p * 260 + ck * 8 + 4] = hi;
      *(short8*)&Vh[p * 256 + ck * 8] = *(const short8*)(kr + 256);
    } else {
      *(u64*)&Kh[p * 260 + ck * 8] = 0ull;
      *(u64*)&Kh[p * 260 + ck * 8 + 4] = 0ull;
      short8 z = {0, 0, 0, 0, 0, 0, 0, 0};
      *(short8*)&Vh[p * 256 + ck * 8] = z;
    }
  }
  __syncthreads();

  // ---- scores + softmax: wave wv owns query p = wv ----
  {
    const int h = lane >> 3, mg = lane & 7;
    const int p = wv;
    const int qi = p >> 2, qj = p & 3;
    const int iq = i0 + qi, jq = j0 + qj;
    const ushort* qp = qkv + (size_t)(iq * 56 + jq) * 768 + h * 32;
    float qf[32];
    #pragma unroll
    for (int u = 0; u < 4; ++u) {
      short8 qv = *(const short8*)(qp + u * 8);
      #pragma unroll
      for (int e = 0; e < 8; ++e) qf[u * 8 + e] = bf2f((ushort)qv[e]);
    }
    float sv[7];
    float mx = -1e30f;
    #pragma unroll
    for (int k = 0; k < 7; ++k) {
      int m = mg + 8 * k;
      float s = -1e30f;
      if (m < 49) {
        int mi = m / 7, mj = m % 7;
        int ii = iq + mi - 3, jj = jq + mj - 3;
        if (ii >= 0 && ii < 56 && jj >= 0 && jj < 56) {
          int hrow = (qi + mi) * 10 + (qj + mj);
          const u64* k8 = (const u64*)&Kh[hrow * 260 + h * 32];
          float a = 0.f;
          #pragma unroll
          for (int u = 0; u < 8; ++u) {
            u64 kv = k8[u];
            #pragma unroll
            for (int e = 0; e < 4; ++e)
              a += qf[u * 4 + e] * bf2f((ushort)(kv >> (16 * e)));
          }
          s = a;
        }
      }
      sv[k] = s;
      mx = fmaxf(mx, s);
    }
    mx = fmaxf(mx, __shfl_xor(mx, 1));
    mx = fmaxf(mx, __shfl_xor(mx, 2));
    mx = fmaxf(mx, __shfl_xor(mx, 4));
    float sm = 0.f;
    #pragma unroll
    for (int k = 0; k < 7; ++k) { sv[k] = __expf(sv[k] - mx); sm += sv[k]; }
    sm += __shfl_xor(sm, 1);
    sm += __shfl_xor(sm, 2);
    sm += __shfl_xor(sm, 4);
    float inv = 1.f / sm;
    #pragma unroll
    for (int k = 0; k < 7; ++k) {
      int m = mg + 8 * k;
      pr[(p * 8 + h) * 67 + m] = sv[k] * inv;
    }
  }
  __syncthreads();     // Kh dead; pr visible

  // proj weights -> registers (8 x dwordx4/lane); land under PV compute.
  short8 pwreg[8];
  #pragma unroll
  for (int kt = 0; kt < 8; ++kt)
    pwreg[kt] = *(const short8*)&pw_bf[(size_t)(wv * 16 + fm) * 256 + kt * 32 + q * 8];

  // ---- PV: thread = (query p = tid>>6, 4-ch group c4 = tid&63) ----
  {
    const int p = tid >> 6, c4 = tid & 63, hh = c4 >> 3;
    const int qi = p >> 2, qj = p & 3;
    float acc4[4] = {0, 0, 0, 0};
    #pragma unroll
    for (int mi = 0; mi < 7; ++mi)
      #pragma unroll
      for (int mj = 0; mj < 7; ++mj) {
        int m = mi * 7 + mj;
        int hrow = (qi + mi) * 10 + (qj + mj);
        float pm = pr[(p * 8 + hh) * 67 + m];
        u64 v4 = *(const u64*)&Vh[hrow * 256 + c4 * 4];
        #pragma unroll
        for (int e = 0; e < 4; ++e)
          acc4[e] += pm * bf2f((ushort)(v4 >> (16 * e)));
      }
    ushort4v o;
    #pragma unroll
    for (int e = 0; e < 4; ++e) o[e] = f2bf(acc4[e]);
    *(ushort4v*)&aas[p * 264 + c4 * 4] = o;
  }
  __syncthreads();     // aas visible; pr/Vh dead

  // ---- proj: wave wv -> out ch [16wv,16wv+16), all 16 px; resid from x ----
  floatx4 xv;
  {
    floatx4 pacc = {0.f, 0.f, 0.f, 0.f};
    #pragma unroll
    for (int kt = 0; kt < 8; ++kt) {
      short8 af = *(const short8*)&aas[fm * 264 + kt * 32 + q * 8];
      pacc = __builtin_amdgcn_mfma_f32_16x16x32_bf16(af, pwreg[kt], pacc, 0, 0, 0);
    }
    int ch = wv * 16 + fm;
    floatx4 rx = *(const floatx4*)(x + (size_t)ch * 3136 + (i0 + q) * 56 + j0);
    #pragma unroll
    for (int r = 0; r < 4; ++r) {
      int px = q * 4 + r;
      x1s[px * 264 + ch] = pacc[r] + projb[ch] + rx[r];
    }
  }
  __syncthreads();     // x1s complete

  // fc1 weight prologue: depth-2 prefetch into regs (lands across LN2 barriers)
  // frag(sidx,nt) = f1_bf[hc*256 + kt*32 + q*8], hc=(wv+(sidx>>3)*16)*32+nt*16+fm
#define F1W(sidx, nt) \
  (*(const short8*)&f1_bf[(size_t)((wv + ((sidx) >> 3) * 16) * 32 + (nt) * 16 + fm) * 256 + ((sidx) & 7) * 32 + q * 8])
  short8 c0 = F1W(0, 0), c1 = F1W(0, 1);
  short8 d0 = F1W(1, 0), d1 = F1W(1, 1);

  // ---- LN2 from x1s; residual kept in regs (matches fc2 acc layout) ----
  xv = *(const floatx4*)&x1s[fm * 264 + wv * 16 + q * 4];
  {
    float s = xv[0] + xv[1] + xv[2] + xv[3];
    float ss = xv[0]*xv[0] + xv[1]*xv[1] + xv[2]*xv[2] + xv[3]*xv[3];
    s += __shfl_xor(s, 16); ss += __shfl_xor(ss, 16);
    s += __shfl_xor(s, 32); ss += __shfl_xor(ss, 32);
    if (lane < 16) { pstat[(wv * 16 + lane) * 2] = s; pstat[(wv * 16 + lane) * 2 + 1] = ss; }
  }
  __syncthreads();
  if (tid < 16) {
    float s2 = 0.f, ss2 = 0.f;
    #pragma unroll
    for (int ww = 0; ww < 16; ++ww) {
      s2 += pstat[(ww * 16 + tid) * 2];
      ss2 += pstat[(ww * 16 + tid) * 2 + 1];
    }
    float mu = s2 * (1.f / 256.f);
    float var = ss2 * (1.f / 256.f) - mu * mu;
    stats[tid * 2] = mu;
    stats[tid * 2 + 1] = rsqrtf(var + 1e-5f);
  }
  __syncthreads();
  {
    float mu = stats[fm * 2], rs = stats[fm * 2 + 1];
    int ch0 = wv * 16 + q * 4;
    ushort4v o;
    #pragma unroll
    for (int e = 0; e < 4; ++e)
      o[e] = f2bf((xv[e] - mu) * rs * n2w[ch0 + e] + n2b[ch0 + e]);
    int slot = ch0 >> 3;
    *(ushort4v*)&t2s[fm * 256 + ((slot ^ (fm & 7)) * 8) + (ch0 & 7)] = o;
  }
  // fc1 bias for this wave's 32-col chunks {wv, wv+16}
  float f1br[2][2];
  #pragma unroll
  for (int ci = 0; ci < 2; ++ci)
    #pragma unroll
    for (int nt = 0; nt < 2; ++nt)
      f1br[ci][nt] = f1b[(wv + ci * 16) * 32 + nt * 16 + fm];
  __syncthreads();     // t2s complete

  // ---- fc1: wave wv -> 2 chunks of 32 h-cols; gelu -> hbuf; reg-weights ----
  {
    floatx4 fa[2] = {{0.f,0.f,0.f,0.f},{0.f,0.f,0.f,0.f}};
    #pragma unroll
    for (int sidx = 0; sidx < 16; ++sidx) {
      const int kt = sidx & 7;
      const int ci = sidx >> 3;
      short8 e0 = {}, e1 = {};
      if (sidx < 14) { e0 = F1W(sidx + 2, 0); e1 = F1W(sidx + 2, 1); }
      short8 af = *(const short8*)&t2s[fm * 256 + (((kt * 4 + q) ^ (fm & 7)) * 8)];
      fa[0] = __builtin_amdgcn_mfma_f32_16x16x32_bf16(af, c0, fa[0], 0, 0, 0);
      fa[1] = __builtin_amdgcn_mfma_f32_16x16x32_bf16(af, c1, fa[1], 0, 0, 0);
      if (kt == 7) {
        #pragma unroll
        for (int nt = 0; nt < 2; ++nt) {
          int hc = (wv + ci * 16) * 32 + nt * 16 + fm;
          #pragma unroll
          for (int r4 = 0; r4 < 4; ++r4) {
            int prow = q * 4 + r4;
            float v = fa[nt][r4] + f1br[ci][nt];
            v = 0.5f * v * (1.0f + erff(v * 0.70710678118654752f));
            hbuf[prow * 1024 + (((hc >> 3) ^ (prow & 7)) * 8) + (hc & 7)] = f2bf(v);
            fa[nt][r4] = 0.f;
          }
        }
      }
      c0 = d0; c1 = d1; d0 = e0; d1 = e1;
    }
  }
#undef F1W

  // fc2 weight prologue: depth-3 prefetch (issued before hbuf barrier)
#define F2W(kt) \
  (*(const short8*)&f2_bf[(size_t)(wv * 16 + fm) * 1024 + (kt) * 32 + q * 8])
  short8 w0 = F2W(0), w1 = F2W(1), w2 = F2W(2);
  __syncthreads();     // hbuf complete

  // ---- fc2: wave wv -> out ch [16wv,16wv+16); residual from regs ----
  {
    floatx4 ga = {0.f, 0.f, 0.f, 0.f};
    #pragma unroll
    for (int kt = 0; kt < 32; ++kt) {
      short8 wn = {};
      if (kt < 29) wn = F2W(kt + 3);
      short8 bfr = *(const short8*)&hbuf[fm * 1024 + (((kt * 4 + q) ^ (fm & 7)) * 8)];
      ga = __builtin_amdgcn_mfma_f32_16x16x32_bf16(w0, bfr, ga, 0, 0, 0);
      w0 = w1; w1 = w2; w2 = wn;
    }
    #pragma unroll
    for (int r4 = 0; r4 < 4; ++r4) {
      int ch = wv * 16 + q * 4 + r4;
      int n = (i0 + (fm >> 2)) * 56 + j0 + (fm & 3);
      outf[(size_t)ch * 3136 + n] = ga[r4] + f2b[ch] + xv[r4];
    }
  }
#undef F2W
}

// ---------------------------------------------------------------------------
extern "C" void kernel_launch(void* const* d_in, const int* in_sizes, int n_in,
                              void* d_out, int out_size, void* d_ws, size_t ws_size,
                              hipStream_t stream) {
  const float* x     = (const float*)d_in[0];
  const float* n1w   = (const float*)d_in[1];
  const float* n1b   = (const float*)d_in[2];
  const float* qkvw  = (const float*)d_in[3];
  const float* qkvb  = (const float*)d_in[4];
  const float* projw = (const float*)d_in[5];
  const float* projb = (const float*)d_in[6];
  const float* n2w   = (const float*)d_in[7];
  const float* n2b   = (const float*)d_in[8];
  const float* f1w   = (const float*)d_in[9];
  const float* f1b   = (const float*)d_in[10];
  const float* f2w   = (const float*)d_in[11];
  const float* f2b   = (const float*)d_in[12];

  char* ws = (char*)d_ws;
  ushort* wcat = (ushort*)(ws + 0);            // 786432 bf16
  ushort* t    = (ushort*)(ws + 4784128);      // 802816 bf16 (t1)
  ushort* qh   = (ushort*)(ws + 6389760);      // qkv [3136][768]

  const ushort* qw_bf = wcat;
  const ushort* pw_bf = wcat + 196608;
  const ushort* f1_bf = wcat + 262144;
  const ushort* f2_bf = wcat + 524288;
  float* outf = (float*)d_out;

  hipLaunchKernelGGL(prep_kernel, dim3(388), dim3(256), 0, stream,
                     x, n1w, n1b, qkvw, t, wcat);
  hipLaunchKernelGGL(qkv_kernel, dim3(12, 97), dim3(256), 0, stream,
                     t, qw_bf, qkvb, qh, projw, f1w, f2w, wcat);
  hipLaunchKernelGGL(attnmlp_kernel, dim3(196), dim3(1024), 0, stream,
                     qh, pw_bf, projb, x, f1_bf, f1b, f2_bf, f2b,
                     n2w, n2b, outf);
}

// Round 5
// 120.658 us; speedup vs baseline: 1.1121x; 1.1121x over previous
//
#include <hip/hip_runtime.h>
#include <math.h>

// ---------------------------------------------------------------------------
// LocalTransformerBlock2d: B=1, C=256, H=W=56 (N=3136), 8 heads x d=32,
// 7x7 local window. fp32 in/out; bf16 MFMA GEMMs.
// R20 (from R19=134us post-mortem): fc1/fc2 reg-rotation reverted to R18's
// global_load_lds slab rings (reg depth 2-3 = ~80cy cover vs 200-900cy
// latency -> +10us; slabs WERE the latency hiding). Kept from R19:
//  - proj weights reg-preload (8 loads issued before PV, consumed after
//    barrier+PV phase = correct issue-early pattern; bit-identical R19).
// New: fc2 ring deepened 3->4 slabs (fits existing fslab region exactly),
// wait vmcnt(3) -> one more load in flight across the 32-iter chain.
// prep/qkv byte-identical to R18.
// ---------------------------------------------------------------------------

typedef unsigned int uint;
typedef unsigned short ushort;
typedef unsigned long long u64;
typedef __attribute__((ext_vector_type(8))) short short8;   // 8 bf16
typedef __attribute__((ext_vector_type(4))) float floatx4;  // MFMA acc
typedef __attribute__((ext_vector_type(4))) unsigned short ushort4v;

#define AS1(p) (const __attribute__((address_space(1))) void*)(p)
#define AS3(p) (__attribute__((address_space(3))) void*)(p)

__device__ __forceinline__ float bf2f(ushort u) {
  union { uint i; float f; } v; v.i = ((uint)u) << 16; return v.f;
}
__device__ __forceinline__ ushort f2bf(float f) {
  union { float f; uint i; } v; v.f = f;
  uint u = v.i;
  return (ushort)((u + 0x7fffu + ((u >> 16) & 1u)) >> 16);
}

// Stage a 64-row x 256-col bf16 panel into LDS with XOR swizzle (qkv kernel).
__device__ __forceinline__ void stage64(const ushort* src, int kstride,
                                        ushort* dstBase, int tid) {
  const int srow = tid >> 5;
  const int scb  = (tid & 31) ^ srow;
  const ushort* g = src + (size_t)srow * kstride + scb * 8;
  ushort* d = dstBase + tid * 8;
  #pragma unroll
  for (int r = 0; r < 8; ++r) {
    __builtin_amdgcn_global_load_lds(AS1(g), AS3(d), 16, 0, 0);
    g += 8 * kstride;
    d += 2048;
  }
}

__device__ __forceinline__ void compute64(const ushort* As, const ushort* Bs,
                                          int w, int lane, floatx4 acc[4]) {
  const int fm = lane & 15;
  const int q  = lane >> 4;
  const int swz = fm & 7;
  const int arow = (w * 16 + fm) * 256;
  #pragma unroll
  for (int kt = 0; kt < 8; ++kt) {
    const int blk = ((kt * 4 + q) ^ swz) * 8;
    short8 af = *(const short8*)&As[arow + blk];
    #pragma unroll
    for (int nt = 0; nt < 4; ++nt) {
      short8 bfr = *(const short8*)&Bs[(nt * 16 + fm) * 256 + blk];
      acc[nt] = __builtin_amdgcn_mfma_f32_16x16x32_bf16(af, bfr, acc[nt], 0, 0, 0);
    }
  }
}

// ---------------------------------------------------------------------------
// prep: blocks 0..195 LN1+transpose (16 px each); blocks 196..387 cvt of
// qkvw (49152 float4s), 1 float4 per thread.
// ---------------------------------------------------------------------------
__global__ __launch_bounds__(256) void prep_kernel(
    const float* __restrict__ x, const float* __restrict__ n1w,
    const float* __restrict__ n1b, const float* __restrict__ qkvw,
    ushort* __restrict__ t1, ushort* __restrict__ wcat)
{
  const int tid = threadIdx.x;
  const int bid = blockIdx.x;
  if (bid >= 196) {
    int idx4 = (bid - 196) * 256 + tid;      // < 49152 float4s
    const float4 v = ((const float4*)qkvw)[idx4];
    ushort4v o = { f2bf(v.x), f2bf(v.y), f2bf(v.z), f2bf(v.w) };
    *(ushort4v*)&wcat[(size_t)idx4 * 4] = o;
    return;
  }
  __shared__ float tile[256 * 17];
  __shared__ float red[2][16][16];
  __shared__ float mu[16], rsv[16];
  const int n0 = bid * 16;
  const int px = tid & 15, grp = tid >> 4;
  {
    // vectorized load: thread c = tid owns channel row c, 16 px = 4 float4
    const float4* xr = (const float4*)&x[(size_t)tid * 3136 + n0];
    #pragma unroll
    for (int k = 0; k < 4; ++k) {
      float4 v = xr[k];
      float* tr = &tile[tid * 17 + k * 4];
      tr[0] = v.x; tr[1] = v.y; tr[2] = v.z; tr[3] = v.w;
    }
  }
  __syncthreads();
  float s = 0.f, ss = 0.f;
  #pragma unroll
  for (int i = 0; i < 16; ++i) {
    float v = tile[(grp * 16 + i) * 17 + px];
    s += v; ss += v * v;
  }
  red[0][px][grp] = s; red[1][px][grp] = ss;
  __syncthreads();
  if (tid < 16) {
    float s2 = 0.f, ss2 = 0.f;
    #pragma unroll
    for (int g = 0; g < 16; ++g) { s2 += red[0][tid][g]; ss2 += red[1][tid][g]; }
    float m = s2 * (1.f / 256.f);
    float var = ss2 * (1.f / 256.f) - m * m;
    mu[tid] = m;
    rsv[tid] = rsqrtf(var + 1e-5f);
  }
  __syncthreads();
  const float wc = n1w[tid], bc = n1b[tid];
  #pragma unroll 4
  for (int p = 0; p < 16; ++p) {
    float v = tile[tid * 17 + p];
    t1[(size_t)(n0 + p) * 256 + tid] = f2bf((v - mu[p]) * rsv[p] * wc + bc);
  }
}

// ---------------------------------------------------------------------------
// qkv: grid (12, 97). y<49: GEMM [3136,256]@[768,256]^T + bias (q scaled).
// y>=49: float4 cvt of pw|f1|f2 (147456 float4s) -- no dependency on GEMM,
// overlaps it and re-warms L2 with weights for attnmlp.
// ---------------------------------------------------------------------------
__global__ __launch_bounds__(256, 4) void qkv_kernel(
    const ushort* __restrict__ A, const ushort* __restrict__ B,
    const float* __restrict__ bias, ushort* __restrict__ out,
    const float* __restrict__ projw, const float* __restrict__ f1w,
    const float* __restrict__ f2w, ushort* __restrict__ wcat)
{
  const int tid = threadIdx.x;
  if (blockIdx.y >= 49) {
    int idx4 = ((blockIdx.y - 49) * 12 + blockIdx.x) * 256 + tid;  // < 147456
    const float* s; int off;
    if (idx4 < 16384)       { s = projw; off = idx4; }
    else if (idx4 < 81920)  { s = f1w;   off = idx4 - 16384; }
    else                    { s = f2w;   off = idx4 - 81920; }
    const float4 v = ((const float4*)s)[off];
    ushort4v o = { f2bf(v.x), f2bf(v.y), f2bf(v.z), f2bf(v.w) };
    *(ushort4v*)&wcat[196608 + (size_t)idx4 * 4] = o;
    return;
  }
  __shared__ ushort As[16384], Bs[16384];
  const int lane = tid & 63, w = tid >> 6;
  const int m0 = blockIdx.y * 64, n0 = blockIdx.x * 64;
  floatx4 acc[4] = {{0.f,0.f,0.f,0.f},{0.f,0.f,0.f,0.f},
                    {0.f,0.f,0.f,0.f},{0.f,0.f,0.f,0.f}};
  stage64(A + (size_t)m0 * 256, 256, As, tid);
  stage64(B + (size_t)n0 * 256, 256, Bs, tid);
  asm volatile("s_waitcnt vmcnt(0)" ::: "memory");
  __syncthreads();
  compute64(As, Bs, w, lane, acc);
  const int fm = lane & 15, q4 = (lane >> 4) * 4;
  #pragma unroll
  for (int nt = 0; nt < 4; ++nt)
    #pragma unroll
    for (int r = 0; r < 4; ++r) {
      int m = m0 + w * 16 + q4 + r;
      int n = n0 + nt * 16 + fm;
      float v = acc[nt][r] + bias[n];
      if (n < 256) v *= 0.17677669529663687f;   // 1/sqrt(32) on q
      out[(size_t)m * 768 + n] = f2bf(v);
    }
}

// ---------------------------------------------------------------------------
// attnmlp: 4x4 query tile per block (grid 196), 1024 threads (4 waves/SIMD).
// LDS (byte offsets; regions reused across phases):
//  attn: Kh@0 (52000) | Vh@52000 (51200) | pr@103200 f32 s67 (34304)
//        aas@137504 (8448) | pstat@145952 (2048) | stats@148000 (128)
//  proj: x1s@103200 f32[16][264] (pr dead); proj weights in registers
//  mlp : hbuf@0 (32768) | fslab@32768 16wv x 4KB = 64KB | t2s@120096
// Per-wave ownership: scores q=wv | proj ch [16wv,16wv+16) | fc1 h-cols
// {32wv..+32, 32(wv+16)..+32} | fc2 ch [16wv,16wv+16).
// ---------------------------------------------------------------------------
#define AM_SMEM 148128

__global__ __launch_bounds__(1024, 1) void attnmlp_kernel(
    const ushort* __restrict__ qkv, const ushort* __restrict__ pw_bf,
    const float* __restrict__ projb, const float* __restrict__ x,
    const ushort* __restrict__ f1_bf, const float* __restrict__ f1b,
    const ushort* __restrict__ f2_bf, const float* __restrict__ f2b,
    const float* __restrict__ n2w, const float* __restrict__ n2b,
    float* __restrict__ outf)
{
  __shared__ __align__(16) char smem[AM_SMEM];
  ushort* Kh    = (ushort*)smem;
  ushort* Vh    = (ushort*)(smem + 52000);
  float*  pr    = (float*)(smem + 103200);       // [16*8][67]
  ushort* aas   = (ushort*)(smem + 137504);      // [16][264]
  float*  x1s   = (float*)(smem + 103200);       // [16][264] f32 (pr dead)
  ushort* hbuf  = (ushort*)smem;                 // [16][1024] (Kh dead)
  ushort* fslab = (ushort*)(smem + 32768);       // 16wv x 2048 ushorts
  ushort* t2s   = (ushort*)(smem + 120096);      // [16][256]
  float*  pstat = (float*)(smem + 145952);       // [16][16][2]
  float*  stats = (float*)(smem + 148000);       // [16][2]

  const int tid = threadIdx.x;
  const int wv = tid >> 6, lane = tid & 63;
  const int fm = lane & 15, q = lane >> 4;
  const int l4 = lane >> 2, lb = lane & 3;
  const int i0 = (blockIdx.x / 14) * 4, j0 = (blockIdx.x % 14) * 4;

  // ---- halo load (zero-fill out-of-image) ----
  for (int s = tid; s < 3200; s += 1024) {
    int p = s >> 5, ck = s & 31;
    int ii = i0 - 3 + p / 10, jj = j0 - 3 + p % 10;
    if (ii >= 0 && ii < 56 && jj >= 0 && jj < 56) {
      const ushort* kr = qkv + (size_t)(ii * 56 + jj) * 768 + 256 + ck * 8;
      short8 kv = *(const short8*)kr;
      u64 lo = ((const u64*)&kv)[0], hi = ((const u64*)&kv)[1];
      *(u64*)&Kh[p * 260 + ck * 8] = lo;
      *(u64*)&Kh[p * 260 + ck * 8 + 4] = hi;
      *(short8*)&Vh[p * 256 + ck * 8] = *(const short8*)(kr + 256);
    } else {
      *(u64*)&Kh[p * 260 + ck * 8] = 0ull;
      *(u64*)&Kh[p * 260 + ck * 8 + 4] = 0ull;
      short8 z = {0, 0, 0, 0, 0, 0, 0, 0};
      *(short8*)&Vh[p * 256 + ck * 8] = z;
    }
  }
  __syncthreads();

  // ---- scores + softmax: wave wv owns query p = wv ----
  {
    const int h = lane >> 3, mg = lane & 7;
    const int p = wv;
    const int qi = p >> 2, qj = p & 3;
    const int iq = i0 + qi, jq = j0 + qj;
    const ushort* qp = qkv + (size_t)(iq * 56 + jq) * 768 + h * 32;
    float qf[32];
    #pragma unroll
    for (int u = 0; u < 4; ++u) {
      short8 qv = *(const short8*)(qp + u * 8);
      #pragma unroll
      for (int e = 0; e < 8; ++e) qf[u * 8 + e] = bf2f((ushort)qv[e]);
    }
    float sv[7];
    float mx = -1e30f;
    #pragma unroll
    for (int k = 0; k < 7; ++k) {
      int m = mg + 8 * k;
      float s = -1e30f;
      if (m < 49) {
        int mi = m / 7, mj = m % 7;
        int ii = iq + mi - 3, jj = jq + mj - 3;
        if (ii >= 0 && ii < 56 && jj >= 0 && jj < 56) {
          int hrow = (qi + mi) * 10 + (qj + mj);
          const u64* k8 = (const u64*)&Kh[hrow * 260 + h * 32];
          float a = 0.f;
          #pragma unroll
          for (int u = 0; u < 8; ++u) {
            u64 kv = k8[u];
            #pragma unroll
            for (int e = 0; e < 4; ++e)
              a += qf[u * 4 + e] * bf2f((ushort)(kv >> (16 * e)));
          }
          s = a;
        }
      }
      sv[k] = s;
      mx = fmaxf(mx, s);
    }
    mx = fmaxf(mx, __shfl_xor(mx, 1));
    mx = fmaxf(mx, __shfl_xor(mx, 2));
    mx = fmaxf(mx, __shfl_xor(mx, 4));
    float sm = 0.f;
    #pragma unroll
    for (int k = 0; k < 7; ++k) { sv[k] = __expf(sv[k] - mx); sm += sv[k]; }
    sm += __shfl_xor(sm, 1);
    sm += __shfl_xor(sm, 2);
    sm += __shfl_xor(sm, 4);
    float inv = 1.f / sm;
    #pragma unroll
    for (int k = 0; k < 7; ++k) {
      int m = mg + 8 * k;
      pr[(p * 8 + h) * 67 + m] = sv[k] * inv;
    }
  }
  __syncthreads();     // Kh dead; pr visible

  // proj weights -> registers (8 x dwordx4/lane); issued before PV, consumed
  // after the aas barrier -> full PV phase of latency cover (R19-verified).
  short8 pwreg[8];
  #pragma unroll
  for (int kt = 0; kt < 8; ++kt)
    pwreg[kt] = *(const short8*)&pw_bf[(size_t)(wv * 16 + fm) * 256 + kt * 32 + q * 8];

  // ---- PV: thread = (query p = tid>>6, 4-ch group c4 = tid&63) ----
  {
    const int p = tid >> 6, c4 = tid & 63, hh = c4 >> 3;
    const int qi = p >> 2, qj = p & 3;
    float acc4[4] = {0, 0, 0, 0};
    #pragma unroll
    for (int mi = 0; mi < 7; ++mi)
      #pragma unroll
      for (int mj = 0; mj < 7; ++mj) {
        int m = mi * 7 + mj;
        int hrow = (qi + mi) * 10 + (qj + mj);
        float pm = pr[(p * 8 + hh) * 67 + m];
        u64 v4 = *(const u64*)&Vh[hrow * 256 + c4 * 4];
        #pragma unroll
        for (int e = 0; e < 4; ++e)
          acc4[e] += pm * bf2f((ushort)(v4 >> (16 * e)));
      }
    ushort4v o;
    #pragma unroll
    for (int e = 0; e < 4; ++e) o[e] = f2bf(acc4[e]);
    *(ushort4v*)&aas[p * 264 + c4 * 4] = o;
  }
  __syncthreads();     // aas visible; pr/Vh dead

  // ---- proj: wave wv -> out ch [16wv,16wv+16), all 16 px; resid from x ----
  floatx4 xv;
  {
    floatx4 pacc = {0.f, 0.f, 0.f, 0.f};
    #pragma unroll
    for (int kt = 0; kt < 8; ++kt) {
      short8 af = *(const short8*)&aas[fm * 264 + kt * 32 + q * 8];
      pacc = __builtin_amdgcn_mfma_f32_16x16x32_bf16(af, pwreg[kt], pacc, 0, 0, 0);
    }
    int ch = wv * 16 + fm;
    floatx4 rx = *(const floatx4*)(x + (size_t)ch * 3136 + (i0 + q) * 56 + j0);
    #pragma unroll
    for (int r = 0; r < 4; ++r) {
      int px = q * 4 + r;
      x1s[px * 264 + ch] = pacc[r] + projb[ch] + rx[r];
    }
  }
  // fc1 prologue: stage 0 into own fslab region (dead Vh; post-PV barrier)
  ushort* fs0 = fslab + wv * 2048;
  ushort* fs1 = fs0 + 1024;
#define STAGE_F1(c, kt, buf) do { \
    _Pragma("unroll") \
    for (int i_ = 0; i_ < 2; ++i_) { \
      int row_ = i_ * 16 + l4; \
      const ushort* g_ = f1_bf + (size_t)((c) * 32 + row_) * 256 + (kt) * 32 + (lb ^ (row_ & 3)) * 8; \
      __builtin_amdgcn_global_load_lds(AS1(g_), AS3((buf) + i_ * 512 + lane * 8), 16, 0, 0); \
    } } while (0)
  STAGE_F1(wv, 0, fs0);
  __syncthreads();     // x1s complete

  // ---- LN2 from x1s; residual kept in regs (matches fc2 acc layout) ----
  xv = *(const floatx4*)&x1s[fm * 264 + wv * 16 + q * 4];
  {
    float s = xv[0] + xv[1] + xv[2] + xv[3];
    float ss = xv[0]*xv[0] + xv[1]*xv[1] + xv[2]*xv[2] + xv[3]*xv[3];
    s += __shfl_xor(s, 16); ss += __shfl_xor(ss, 16);
    s += __shfl_xor(s, 32); ss += __shfl_xor(ss, 32);
    if (lane < 16) { pstat[(wv * 16 + lane) * 2] = s; pstat[(wv * 16 + lane) * 2 + 1] = ss; }
  }
  __syncthreads();
  if (tid < 16) {
    float s2 = 0.f, ss2 = 0.f;
    #pragma unroll
    for (int ww = 0; ww < 16; ++ww) {
      s2 += pstat[(ww * 16 + tid) * 2];
      ss2 += pstat[(ww * 16 + tid) * 2 + 1];
    }
    float mu = s2 * (1.f / 256.f);
    float var = ss2 * (1.f / 256.f) - mu * mu;
    stats[tid * 2] = mu;
    stats[tid * 2 + 1] = rsqrtf(var + 1e-5f);
  }
  __syncthreads();
  {
    float mu = stats[fm * 2], rs = stats[fm * 2 + 1];
    int ch0 = wv * 16 + q * 4;
    ushort4v o;
    #pragma unroll
    for (int e = 0; e < 4; ++e)
      o[e] = f2bf((xv[e] - mu) * rs * n2w[ch0 + e] + n2b[ch0 + e]);
    int slot = ch0 >> 3;
    *(ushort4v*)&t2s[fm * 256 + ((slot ^ (fm & 7)) * 8) + (ch0 & 7)] = o;
  }
  // fc1 bias for this wave's 32-col chunks {wv, wv+16}
  float f1br[2][2];
  #pragma unroll
  for (int ci = 0; ci < 2; ++ci)
    #pragma unroll
    for (int nt = 0; nt < 2; ++nt)
      f1br[ci][nt] = f1b[(wv + ci * 16) * 32 + nt * 16 + fm];
  __syncthreads();     // t2s complete

  // ---- fc1: wave wv -> 2 chunks of 32 h-cols; gelu -> hbuf; dbuf-2 ----
  {
    floatx4 fa[2] = {{0.f,0.f,0.f,0.f},{0.f,0.f,0.f,0.f}};
    for (int sidx = 0; sidx < 16; ++sidx) {
      const int kt = sidx & 7;
      const int ci = sidx >> 3;
      ushort* cur = (sidx & 1) ? fs1 : fs0;
      ushort* nxt = (sidx & 1) ? fs0 : fs1;
      if (sidx < 15) {
        int s1 = sidx + 1;
        STAGE_F1(wv + (s1 >> 3) * 16, s1 & 7, nxt);
        asm volatile("s_waitcnt vmcnt(2)" ::: "memory");
      } else {
        asm volatile("s_waitcnt vmcnt(0)" ::: "memory");
      }
      short8 af = *(const short8*)&t2s[fm * 256 + (((kt * 4 + q) ^ (fm & 7)) * 8)];
      #pragma unroll
      for (int nt = 0; nt < 2; ++nt) {
        int r = nt * 16 + fm;
        short8 bfr = *(const short8*)&cur[r * 32 + (q ^ (r & 3)) * 8];
        fa[nt] = __builtin_amdgcn_mfma_f32_16x16x32_bf16(af, bfr, fa[nt], 0, 0, 0);
      }
      if (kt == 7) {
        #pragma unroll
        for (int nt = 0; nt < 2; ++nt) {
          int hc = (wv + ci * 16) * 32 + nt * 16 + fm;
          #pragma unroll
          for (int r4 = 0; r4 < 4; ++r4) {
            int prow = q * 4 + r4;
            float v = fa[nt][r4] + f1br[ci][nt];
            v = 0.5f * v * (1.0f + erff(v * 0.70710678118654752f));
            hbuf[prow * 1024 + (((hc >> 3) ^ (prow & 7)) * 8) + (hc & 7)] = f2bf(v);
            fa[nt][r4] = 0.f;
          }
        }
      }
    }
  }
  // fc2 ring-4 of 1KB slabs filling the wave's 2048-ushort fslab region
  ushort* gs4[4] = {fs0, fs0 + 512, fs0 + 1024, fs0 + 1536};
#define STAGE_F2(kt, buf) do { \
    const ushort* g_ = f2_bf + (size_t)(wv * 16 + l4) * 1024 + (kt) * 32 + (lb ^ (l4 & 3)) * 8; \
    __builtin_amdgcn_global_load_lds(AS1(g_), AS3((buf) + lane * 8), 16, 0, 0); \
  } while (0)
  STAGE_F2(0, gs4[0]);
  STAGE_F2(1, gs4[1]);
  STAGE_F2(2, gs4[2]);
  __syncthreads();     // hbuf complete (drains prologue stages too)

  // ---- fc2: wave wv -> out ch [16wv,16wv+16); residual from regs ----
  // ring-4 depth-3: read gs4[kt&3], write gs4[(kt+3)&3]; in-flight kt+1..kt+3
  {
    floatx4 ga = {0.f, 0.f, 0.f, 0.f};
    for (int kt = 0; kt < 32; ++kt) {
      if (kt < 29) {
        STAGE_F2(kt + 3, gs4[(kt + 3) & 3]);
        asm volatile("s_waitcnt vmcnt(3)" ::: "memory");   // stage kt landed
      } else if (kt == 29) {
        asm volatile("s_waitcnt vmcnt(2)" ::: "memory");
      } else if (kt == 30) {
        asm volatile("s_waitcnt vmcnt(1)" ::: "memory");
      } else {
        asm volatile("s_waitcnt vmcnt(0)" ::: "memory");
      }
      ushort* cur = gs4[kt & 3];
      short8 af = *(const short8*)&cur[fm * 32 + ((q ^ (fm & 3)) * 8)];
      short8 bfr = *(const short8*)&hbuf[fm * 1024 + (((kt * 4 + q) ^ (fm & 7)) * 8)];
      ga = __builtin_amdgcn_mfma_f32_16x16x32_bf16(af, bfr, ga, 0, 0, 0);
    }
    #pragma unroll
    for (int r4 = 0; r4 < 4; ++r4) {
      int ch = wv * 16 + q * 4 + r4;
      int n = (i0 + (fm >> 2)) * 56 + j0 + (fm & 3);
      outf[(size_t)ch * 3136 + n] = ga[r4] + f2b[ch] + xv[r4];
    }
  }
#undef STAGE_F1
#undef STAGE_F2
}

// ---------------------------------------------------------------------------
extern "C" void kernel_launch(void* const* d_in, const int* in_sizes, int n_in,
                              void* d_out, int out_size, void* d_ws, size_t ws_size,
                              hipStream_t stream) {
  const float* x     = (const float*)d_in[0];
  const float* n1w   = (const float*)d_in[1];
  const float* n1b   = (const float*)d_in[2];
  const float* qkvw  = (const float*)d_in[3];
  const float* qkvb  = (const float*)d_in[4];
  const float* projw = (const float*)d_in[5];
  const float* projb = (const float*)d_in[6];
  const float* n2w   = (const float*)d_in[7];
  const float* n2b   = (const float*)d_in[8];
  const float* f1w   = (const float*)d_in[9];
  const float* f1b   = (const float*)d_in[10];
  const float* f2w   = (const float*)d_in[11];
  const float* f2b   = (const float*)d_in[12];

  char* ws = (char*)d_ws;
  ushort* wcat = (ushort*)(ws + 0);            // 786432 bf16
  ushort* t    = (ushort*)(ws + 4784128);      // 802816 bf16 (t1)
  ushort* qh   = (ushort*)(ws + 6389760);      // qkv [3136][768]

  const ushort* qw_bf = wcat;
  const ushort* pw_bf = wcat + 196608;
  const ushort* f1_bf = wcat + 262144;
  const ushort* f2_bf = wcat + 524288;
  float* outf = (float*)d_out;

  hipLaunchKernelGGL(prep_kernel, dim3(388), dim3(256), 0, stream,
                     x, n1w, n1b, qkvw, t, wcat);
  hipLaunchKernelGGL(qkv_kernel, dim3(12, 97), dim3(256), 0, stream,
                     t, qw_bf, qkvb, qh, projw, f1w, f2w, wcat);
  hipLaunchKernelGGL(attnmlp_kernel, dim3(196), dim3(1024), 0, stream,
                     qh, pw_bf, projb, x, f1_bf, f1b, f2_bf, f2b,
                     n2w, n2b, outf);
}